// Round 2
// baseline (438.666 us; speedup 1.0000x reference)
//
#include <hip/hip_runtime.h>
#include <cstdint>

typedef __attribute__((ext_vector_type(8))) short short8;
typedef __attribute__((ext_vector_type(4))) float floatx4;

__device__ __forceinline__ unsigned short f2bf(float f) {
  uint32_t u = __builtin_bit_cast(uint32_t, f);
  u += 0x7fffu + ((u >> 16) & 1u);   // RNE
  return (unsigned short)(u >> 16);
}
// pack bf16(lo)|bf16(hi)<<16, round-half-up: 2 adds + 1 v_perm
__device__ __forceinline__ uint32_t pkbf(float lo, float hi) {
  uint32_t a = __builtin_bit_cast(uint32_t, lo) + 0x8000u;
  uint32_t b = __builtin_bit_cast(uint32_t, hi) + 0x8000u;
  return __builtin_amdgcn_perm(b, a, 0x07060302);
}

// ---------------- kernel 1: W transpose + convert (fp32 -> bf16) ----------------
__global__ void prep_w_kernel(const float* __restrict__ Wq,
                              const float* __restrict__ Wk,
                              const float* __restrict__ Wv,
                              unsigned short* __restrict__ Wt) {
  int idx = blockIdx.x * 256 + threadIdx.x;
  if (idx >= 576 * 768) return;
  int n = idx / 768;
  int k = idx - n * 768;
  int which = n / 192;
  int nn = n - which * 192;
  const float* W = (which == 0) ? Wq : (which == 1) ? Wk : Wv;
  Wt[idx] = f2bf(W[k * 192 + nn]);
}

// ---------------- kernel 2: fused QKV projection + RoPE ----------------
// One block per 64-row m-tile computes ALL 576 output cols (Q|K|V fused):
//  - A (x fp32->bf16) staged/converted ONCE (was 3x across which-grid)
//  - 36 MFMA per wave per barrier (was 12) to amortize latency windows
//  - register double-buffer prefetch: A (HBM, ~900cy) issued a phase early,
//    B (Wt, L2-resident ~250cy) issued after the barrier under COMPUTE
//  - LDS: unpadded stride-32 rows + XOR 16B-chunk swizzle (slot = c ^ ((row>>1)&3))
//    -> uniform 8 accesses/bank on b128 frag reads (structural minimum)
// Wave w: rows (w&1)*32..+31 (2 row-tiles), cols (w>>1)*288..+287 (18 ntiles).
__global__ __launch_bounds__(256, 2) void proj_kernel(
    const float* __restrict__ x, const unsigned short* __restrict__ Wt,
    unsigned short* __restrict__ q_ws, unsigned short* __restrict__ k_ws,
    unsigned short* __restrict__ v_ws) {
  __shared__ __align__(16) unsigned short A_lds[64 * 32];   // 4 KB
  __shared__ __align__(16) unsigned short B_lds[576 * 32];  // 36 KB
  const int tid = threadIdx.x;
  const int w = tid >> 6, l = tid & 63, quad = l >> 4, ln = l & 15;
  const int wr = w & 1, wc = w >> 1;
  const int m0 = blockIdx.x * 64;

  // staging geometry: each thread owns one 16B chunk (8 bf16) per 64B row
  const int arow = tid >> 2;                         // 0..63
  const int ac = tid & 3;                            // chunk index in row
  const int aslot = ((ac ^ ((tid >> 3) & 3)) << 4);  // swizzled byte slot
  char* Awp = (char*)A_lds + arow * 64 + aslot;
  char* Bwp = (char*)B_lds + arow * 64 + aslot;

  const float* xp = x + (size_t)(m0 + arow) * 768 + ac * 8;
  const unsigned short* bp = Wt + (size_t)arow * 768 + ac * 8;

  // fragment read bases: chunk quad of row (base+ln); (row>>1)&3 == (ln>>1)&3
  // because all row bases are multiples of 8
  const int fq = ((quad ^ ((ln >> 1) & 3)) << 4);
  const char* Arp = (const char*)A_lds + (wr * 32 + ln) * 64 + fq;
  const char* Brp = (const char*)B_lds + (wc * 288 + ln) * 64 + fq;

  floatx4 acc[2][18];
#pragma unroll
  for (int mi = 0; mi < 2; ++mi)
#pragma unroll
    for (int nj = 0; nj < 18; ++nj) acc[mi][nj] = floatx4{0.f, 0.f, 0.f, 0.f};

  float4 a0x, a0y, a1x, a1y;
  uint4 bb0[9], bb1[9];

#define LOADA(AX, AY, K0)                    \
  do {                                       \
    AX = *(const float4*)(xp + (K0));        \
    AY = *(const float4*)(xp + (K0) + 4);    \
  } while (0)
#define LOADB(BB, K0)                                             \
  do {                                                            \
    _Pragma("unroll") for (int it = 0; it < 9; ++it)              \
        (BB)[it] = *(const uint4*)(bp + it * 49152 + (K0));       \
  } while (0)
#define STAGE(AX, AY, BB)                                         \
  do {                                                            \
    uint4 ap;                                                     \
    ap.x = pkbf((AX).x, (AX).y);                                  \
    ap.y = pkbf((AX).z, (AX).w);                                  \
    ap.z = pkbf((AY).x, (AY).y);                                  \
    ap.w = pkbf((AY).z, (AY).w);                                  \
    *(uint4*)Awp = ap;                                            \
    _Pragma("unroll") for (int it = 0; it < 9; ++it)              \
        *(uint4*)(Bwp + it * 4096) = (BB)[it];                    \
  } while (0)
#define PCOMPUTE()                                                               \
  do {                                                                           \
    short8 af0 = *(const short8*)(Arp);                                          \
    short8 af1 = *(const short8*)(Arp + 1024);                                   \
    _Pragma("unroll") for (int nj = 0; nj < 18; ++nj) {                          \
      short8 bf = *(const short8*)(Brp + nj * 1024);                             \
      acc[0][nj] = __builtin_amdgcn_mfma_f32_16x16x32_bf16(af0, bf, acc[0][nj],  \
                                                           0, 0, 0);             \
      acc[1][nj] = __builtin_amdgcn_mfma_f32_16x16x32_bf16(af1, bf, acc[1][nj],  \
                                                           0, 0, 0);             \
    }                                                                            \
  } while (0)

  LOADA(a0x, a0y, 0);
  LOADB(bb0, 0);
  for (int kb = 0; kb < 24; kb += 2) {
    LOADA(a1x, a1y, (kb + 1) * 32);  // HBM load issued a full phase early
    STAGE(a0x, a0y, bb0);
    __syncthreads();
    LOADB(bb1, (kb + 1) * 32);       // L2 load covered by COMPUTE
    PCOMPUTE();
    __syncthreads();
    if (kb < 22) LOADA(a0x, a0y, (kb + 2) * 32);
    STAGE(a1x, a1y, bb1);
    __syncthreads();
    if (kb < 22) LOADB(bb0, (kb + 2) * 32);
    PCOMPUTE();
    __syncthreads();
  }
#undef LOADA
#undef LOADB
#undef STAGE
#undef PCOMPUTE

  // epilogue. global col n = wc*288 + nj*16 + ln; which = n/192.
  // wc==0: nj 0..11 -> Q (RoPE on nj 0,1); nj 12..17 -> K nn 0..95 (RoPE on 12,13)
  // wc==1: nj 0..5  -> K nn 96..191 (no RoPE); nj 6..17 -> V (transposed store)
  if (wc == 0) {
#pragma unroll
    for (int mi = 0; mi < 2; ++mi) {
#pragma unroll
      for (int r = 0; r < 4; ++r) {
        int row_g = m0 + wr * 32 + mi * 16 + quad * 4 + r;
        int t_pos = row_g & 511;
        float vq[2], vk[2];
#pragma unroll
        for (int tt = 0; tt < 2; ++tt) {
          vq[tt] = acc[mi][tt][r];
          vk[tt] = acc[mi][12 + tt][r];
        }
#pragma unroll
        for (int tt = 0; tt < 2; ++tt) {
          int col = tt * 16 + ln;
          int i = col >> 1;
          float inv_freq = exp2f(-(float)i * (13.287712379549449f / 16.0f));
          float ang = (float)t_pos * inv_freq;
          float sv, cv;
          sincosf(ang, &sv, &cv);
          float pq = __shfl_xor(vq[tt], 1);
          float pk = __shfl_xor(vk[tt], 1);
          vq[tt] = (col & 1) ? (vq[tt] * cv + pq * sv) : (vq[tt] * cv - pq * sv);
          vk[tt] = (col & 1) ? (vk[tt] * cv + pk * sv) : (vk[tt] * cv - pk * sv);
        }
#pragma unroll
        for (int nj = 0; nj < 12; ++nj) {
          float v = (nj < 2) ? vq[nj] : acc[mi][nj][r];
          q_ws[(size_t)row_g * 192 + nj * 16 + ln] = f2bf(v);
        }
#pragma unroll
        for (int nj = 0; nj < 6; ++nj) {
          float v = (nj < 2) ? vk[nj] : acc[mi][12 + nj][r];
          k_ws[(size_t)row_g * 192 + nj * 16 + ln] = f2bf(v);
        }
      }
    }
  } else {
#pragma unroll
    for (int mi = 0; mi < 2; ++mi) {
#pragma unroll
      for (int r = 0; r < 4; ++r) {
        int row_g = m0 + wr * 32 + mi * 16 + quad * 4 + r;
#pragma unroll
        for (int nj = 0; nj < 6; ++nj)
          k_ws[(size_t)row_g * 192 + 96 + nj * 16 + ln] = f2bf(acc[mi][nj][r]);
      }
      int rb = m0 + wr * 32 + mi * 16 + quad * 4;  // 4 consecutive rows, same batch
      int bb = rb >> 9, t = rb & 511;
#pragma unroll
      for (int nj = 6; nj < 18; ++nj) {
        ushort4 pv;
        pv.x = f2bf(acc[mi][nj][0]);
        pv.y = f2bf(acc[mi][nj][1]);
        pv.z = f2bf(acc[mi][nj][2]);
        pv.w = f2bf(acc[mi][nj][3]);
        *(ushort4*)&v_ws[((size_t)bb * 192 + (nj - 6) * 16 + ln) * 512 + t] = pv;
      }
    }
  }
}

// ---------------- kernel 3: causal flash attention (MFMA) ----------------
// grid (8, 64). qt remap: dispatch i and i+256 carry complementary qt.
// K/V tile kt+1 register-prefetched (T14) so global latency hides under
// QK/softmax/PV; s_setprio(1) around MFMA clusters (T5, 2 blocks/CU overlap).
__global__ __launch_bounds__(256, 2) void attn_kernel(
    const unsigned short* __restrict__ q_ws, const unsigned short* __restrict__ k_ws,
    const unsigned short* __restrict__ v_ws, float* __restrict__ out) {
  __shared__ __align__(16) unsigned short K_lds[64 * 200];
  __shared__ __align__(16) unsigned short V_lds[192 * 72];   // V^T: [dim][key]
  __shared__ __align__(16) unsigned short P_lds[4][16 * 72]; // per-wave P
  const int tid = threadIdx.x;
  const int w = tid >> 6, l = tid & 63, quad = l >> 4, ln = l & 15;
  const int b = blockIdx.y;
  const int qt = (blockIdx.y < 32) ? blockIdx.x : 7 - blockIdx.x;
  const int q0 = qt * 64;

  // preload Q A-fragments
  short8 qf[6];
  {
    const unsigned short* qp =
        q_ws + (size_t)(b * 512 + q0 + w * 16 + ln) * 192 + quad * 8;
#pragma unroll
    for (int kk = 0; kk < 6; ++kk) qf[kk] = *(const short8*)(qp + kk * 32);
  }

  float m_i[4], l_i[4];
  floatx4 o[12];
#pragma unroll
  for (int r = 0; r < 4; ++r) { m_i[r] = -1e30f; l_i[r] = 0.f; }
#pragma unroll
  for (int nt = 0; nt < 12; ++nt) o[nt] = floatx4{0.f, 0.f, 0.f, 0.f};
  const float sm_scale = 0.07216878364870323f;  // 192^-0.5

  uint4 kpre0[6], vpre0[6], kpre1[6], vpre1[6];

#define AT_LOAD(KB, VB, K0)                                                        \
  do {                                                                             \
    _Pragma("unroll") for (int it = 0; it < 6; ++it) {                             \
      int idx = it * 256 + tid;                                                    \
      int row = idx / 24, c = idx - row * 24;                                      \
      (KB)[it] = *(const uint4*)(k_ws + (size_t)(b * 512 + (K0) + row) * 192 + c * 8); \
    }                                                                              \
    _Pragma("unroll") for (int it = 0; it < 6; ++it) {                             \
      int idx = it * 256 + tid;                                                    \
      int row = idx >> 3, c = idx & 7;                                             \
      (VB)[it] = *(const uint4*)(v_ws + (size_t)(b * 192 + row) * 512 + (K0) + c * 8); \
    }                                                                              \
  } while (0)
#define AT_STAGE(KB, VB)                                      \
  do {                                                        \
    _Pragma("unroll") for (int it = 0; it < 6; ++it) {        \
      int idx = it * 256 + tid;                               \
      int row = idx / 24, c = idx - row * 24;                 \
      *(uint4*)&K_lds[row * 200 + c * 8] = (KB)[it];          \
    }                                                         \
    _Pragma("unroll") for (int it = 0; it < 6; ++it) {        \
      int idx = it * 256 + tid;                               \
      int row = idx >> 3, c = idx & 7;                        \
      *(uint4*)&V_lds[row * 72 + c * 8] = (VB)[it];           \
    }                                                         \
  } while (0)

  AT_LOAD(kpre0, vpre0, 0);

  for (int kt = 0; kt <= qt; ++kt) {
    AT_STAGE(kpre0, vpre0);
    __syncthreads();
    if (kt < qt) AT_LOAD(kpre1, vpre1, (kt + 1) * 64);  // overlaps with compute

    // S = Q K^T (scaled)
    float s[4][4];
    __builtin_amdgcn_s_setprio(1);
#pragma unroll
    for (int nt = 0; nt < 4; ++nt) {
      floatx4 sa = floatx4{0.f, 0.f, 0.f, 0.f};
#pragma unroll
      for (int kk = 0; kk < 6; ++kk) {
        short8 kf = *(const short8*)&K_lds[(nt * 16 + ln) * 200 + kk * 32 + quad * 8];
        sa = __builtin_amdgcn_mfma_f32_16x16x32_bf16(qf[kk], kf, sa, 0, 0, 0);
      }
#pragma unroll
      for (int r = 0; r < 4; ++r) s[nt][r] = sa[r] * sm_scale;
    }
    __builtin_amdgcn_s_setprio(0);
    if (kt == qt) {  // diagonal tile mask (k0 == q0)
#pragma unroll
      for (int nt = 0; nt < 4; ++nt)
#pragma unroll
        for (int r = 0; r < 4; ++r)
          if (nt * 16 + ln > w * 16 + quad * 4 + r) s[nt][r] = -1e30f;
    }
    // online softmax (row = quad*4+r)
    float alpha[4];
#pragma unroll
    for (int r = 0; r < 4; ++r) {
      float mx = fmaxf(fmaxf(s[0][r], s[1][r]), fmaxf(s[2][r], s[3][r]));
      mx = fmaxf(mx, __shfl_xor(mx, 1));
      mx = fmaxf(mx, __shfl_xor(mx, 2));
      mx = fmaxf(mx, __shfl_xor(mx, 4));
      mx = fmaxf(mx, __shfl_xor(mx, 8));
      float mnew = fmaxf(m_i[r], mx);
      alpha[r] = __expf(m_i[r] - mnew);
      float sum = 0.f;
#pragma unroll
      for (int nt = 0; nt < 4; ++nt) {
        s[nt][r] = __expf(s[nt][r] - mnew);
        sum += s[nt][r];
      }
      sum += __shfl_xor(sum, 1);
      sum += __shfl_xor(sum, 2);
      sum += __shfl_xor(sum, 4);
      sum += __shfl_xor(sum, 8);
      l_i[r] = l_i[r] * alpha[r] + sum;
      m_i[r] = mnew;
    }
#pragma unroll
    for (int nt = 0; nt < 12; ++nt)
#pragma unroll
      for (int r = 0; r < 4; ++r) o[nt][r] *= alpha[r];

    // P: C/D layout -> A layout via per-wave LDS
#pragma unroll
    for (int nt = 0; nt < 4; ++nt)
#pragma unroll
      for (int r = 0; r < 4; ++r)
        P_lds[w][(quad * 4 + r) * 72 + nt * 16 + ln] = f2bf(s[nt][r]);
    __asm__ volatile("s_waitcnt lgkmcnt(0)" ::: "memory");  // wave-local write->read

    // O += P V
    __builtin_amdgcn_s_setprio(1);
#pragma unroll
    for (int ks = 0; ks < 2; ++ks) {
      short8 pf = *(const short8*)&P_lds[w][ln * 72 + ks * 32 + quad * 8];
#pragma unroll
      for (int nt = 0; nt < 12; ++nt) {
        short8 vf = *(const short8*)&V_lds[(nt * 16 + ln) * 72 + ks * 32 + quad * 8];
        o[nt] = __builtin_amdgcn_mfma_f32_16x16x32_bf16(pf, vf, o[nt], 0, 0, 0);
      }
    }
    __builtin_amdgcn_s_setprio(0);
    __syncthreads();  // all LDS reads done before next tile's AT_STAGE
    if (kt < qt) {
#pragma unroll
      for (int it = 0; it < 6; ++it) {
        kpre0[it] = kpre1[it];
        vpre0[it] = vpre1[it];
      }
    }
  }
#undef AT_LOAD
#undef AT_STAGE

  // epilogue: O/l -> fp32 out [b][t][dim]
#pragma unroll
  for (int r = 0; r < 4; ++r) {
    float inv = 1.0f / l_i[r];
    size_t rowoff = (size_t)(b * 512 + q0 + w * 16 + quad * 4 + r) * 192;
#pragma unroll
    for (int nt = 0; nt < 12; ++nt)
      out[rowoff + nt * 16 + ln] = o[nt][r] * inv;
  }
}

extern "C" void kernel_launch(void* const* d_in, const int* in_sizes, int n_in,
                              void* d_out, int out_size, void* d_ws, size_t ws_size,
                              hipStream_t stream) {
  const float* x = (const float*)d_in[0];
  const float* Wq = (const float*)d_in[1];
  const float* Wk = (const float*)d_in[2];
  const float* Wv = (const float*)d_in[3];
  float* out = (float*)d_out;

  char* ws = (char*)d_ws;
  const size_t QKV_BYTES = (size_t)64 * 512 * 192 * 2;  // 12,582,912
  unsigned short* q_ws = (unsigned short*)(ws);
  unsigned short* k_ws = (unsigned short*)(ws + QKV_BYTES);
  unsigned short* v_ws = (unsigned short*)(ws + 2 * QKV_BYTES);
  unsigned short* Wt = (unsigned short*)(ws + 3 * QKV_BYTES);

  hipLaunchKernelGGL(prep_w_kernel, dim3(1728), dim3(256), 0, stream, Wq, Wk, Wv, Wt);
  hipLaunchKernelGGL(proj_kernel, dim3(512), dim3(256), 0, stream, x, Wt, q_ws, k_ws, v_ws);
  hipLaunchKernelGGL(attn_kernel, dim3(8, 64), dim3(256), 0, stream, q_ws, k_ws, v_ws, out);
}

// Round 4
// 229.354 us; speedup vs baseline: 1.9126x; 1.9126x over previous
//
#include <hip/hip_runtime.h>
#include <cstdint>

typedef __attribute__((ext_vector_type(8))) short short8;
typedef __attribute__((ext_vector_type(4))) float floatx4;

__device__ __forceinline__ unsigned short f2bf(float f) {
  uint32_t u = __builtin_bit_cast(uint32_t, f);
  u += 0x7fffu + ((u >> 16) & 1u);   // RNE
  return (unsigned short)(u >> 16);
}
// pack bf16(lo)|bf16(hi)<<16, round-half-up: 2 adds + 1 v_perm
__device__ __forceinline__ uint32_t pkbf(float lo, float hi) {
  uint32_t a = __builtin_bit_cast(uint32_t, lo) + 0x8000u;
  uint32_t b = __builtin_bit_cast(uint32_t, hi) + 0x8000u;
  return __builtin_amdgcn_perm(b, a, 0x07060302);
}
// async global->LDS, 16B per lane (HW: wave-uniform LDS base + lane*16)
__device__ __forceinline__ void gll16(const void* g, void* l) {
  __builtin_amdgcn_global_load_lds(
      (const __attribute__((address_space(1))) unsigned int*)g,
      (__attribute__((address_space(3))) unsigned int*)l, 16, 0, 0);
}

// ---------------- kernel 1: build Wt LDS-image (fp32 -> bf16, swizzled) --------
// Image chunk order == the linear order global_load_lds writes LDS in proj:
// [by(2)][kb(24)][row(288)][cs(4)] 16B chunks; chunk cs holds data k-chunk
// c = cs ^ ((row>>1)&3)  (XOR bank swizzle baked into the image).
__global__ void prep_w_kernel(const float* __restrict__ Wq,
                              const float* __restrict__ Wk,
                              const float* __restrict__ Wv,
                              unsigned short* __restrict__ Wt) {
  int id = blockIdx.x * 256 + threadIdx.x;      // 55296 chunks total
  int by = id / 27648, rem = id - by * 27648;
  int kb = rem / 1152, s = rem - kb * 1152;
  int row = s >> 2, cs = s & 3;
  int n = by * 288 + row;                        // global output col 0..575
  int c = cs ^ ((row >> 1) & 3);
  int which = n / 192, nn = n - which * 192;
  const float* W = (which == 0) ? Wq : (which == 1) ? Wk : Wv;
  int k0 = kb * 32 + c * 8;
  unsigned short v[8];
#pragma unroll
  for (int e = 0; e < 8; ++e) v[e] = f2bf(W[(size_t)(k0 + e) * 192 + nn]);
  uint4 o;
  o.x = v[0] | ((uint32_t)v[1] << 16);
  o.y = v[2] | ((uint32_t)v[3] << 16);
  o.z = v[4] | ((uint32_t)v[5] << 16);
  o.w = v[6] | ((uint32_t)v[7] << 16);
  *(uint4*)(Wt + (size_t)id * 8) = o;
}

// ---------------- kernel 2: fused QKV projection + RoPE (v3) ----------------
// grid (512 m-tiles, 2 col-halves). Block: 64 rows x 288 cols, BK=32, 4 waves.
// Wave: rows (w&1)*32 (2 m-tiles), cols (w>>1)*144 (9 ntiles) -> acc[2][9]=72 regs
// (v2's 144acc+72 B-prefetch spilled: WRITE_SIZE 480MB. B now streams via
// global_load_lds from the pre-swizzled Wt image = ZERO staging VGPRs.)
// Both LDS tiles double-buffered -> 1 barrier/K-step; A reg-prefetched 2 ahead.
// LDS 44KB -> 3 blocks/CU (under the 64KB/WG limit).
__global__ __launch_bounds__(256, 3) void proj_kernel(
    const float* __restrict__ x, const unsigned short* __restrict__ Wt,
    unsigned short* __restrict__ q_ws, unsigned short* __restrict__ k_ws,
    unsigned short* __restrict__ v_ws) {
  __shared__ __align__(16) unsigned short A_lds[2][64 * 32];    // 2 x 4KB
  __shared__ __align__(16) unsigned short B_lds[2][288 * 32];   // 2 x 18KB
  const int tid = threadIdx.x;
  const int w = tid >> 6, l = tid & 63, quad = l >> 4, ln = l & 15;
  const int wr = w & 1, wc = w >> 1;
  const int m0 = blockIdx.x * 64;

  // A staging: thread -> one 16B chunk (8 bf16) of one row
  const int arow = tid >> 2, ac = tid & 3;
  const int aslot = ((ac ^ ((arow >> 1) & 3)) << 4);
  const float* xp = x + (size_t)(m0 + arow) * 768 + ac * 8;
  // B image for this col-half: 27648 chunks
  const unsigned short* wimg = Wt + (size_t)blockIdx.y * 27648 * 8;

  // fragment read chunk: (row>>1)&3 == (ln>>1)&3 for all frag rows (bases %8==0)
  const int fq = ((quad ^ ((ln >> 1) & 3)) << 4);

  floatx4 acc[2][9];
#pragma unroll
  for (int mi = 0; mi < 2; ++mi)
#pragma unroll
    for (int nj = 0; nj < 9; ++nj) acc[mi][nj] = floatx4{0.f, 0.f, 0.f, 0.f};

  float4 a0x, a0y;

#define LOADA(K0)                                  \
  do {                                             \
    a0x = *(const float4*)(xp + (K0));             \
    a0y = *(const float4*)(xp + (K0) + 4);         \
  } while (0)
#define STAGEA(BUF)                                               \
  do {                                                            \
    uint4 ap;                                                     \
    ap.x = pkbf(a0x.x, a0x.y);                                    \
    ap.y = pkbf(a0x.z, a0x.w);                                    \
    ap.z = pkbf(a0y.x, a0y.y);                                    \
    ap.w = pkbf(a0y.z, a0y.w);                                    \
    *(uint4*)((char*)&A_lds[BUF][0] + arow * 64 + aslot) = ap;    \
  } while (0)
#define LOADB(KB, BUF)                                               \
  do {                                                               \
    const unsigned short* src = wimg + (size_t)(KB) * 9216;          \
    char* dstb = (char*)&B_lds[BUF][0];                              \
    _Pragma("unroll") for (int it = 0; it < 4; ++it)                 \
        gll16(src + (it * 256 + tid) * 8, dstb + (it * 256 + tid) * 16); \
    if (tid < 128) gll16(src + (1024 + tid) * 8, dstb + (1024 + tid) * 16); \
  } while (0)
#define PCOMPUTE(BUF)                                                            \
  do {                                                                           \
    short8 af0 = *(const short8*)((const char*)&A_lds[BUF][0] +                  \
                                  (wr * 32 + ln) * 64 + fq);                     \
    short8 af1 = *(const short8*)((const char*)&A_lds[BUF][0] +                  \
                                  (wr * 32 + 16 + ln) * 64 + fq);                \
    _Pragma("unroll") for (int nj = 0; nj < 9; ++nj) {                           \
      short8 bf = *(const short8*)((const char*)&B_lds[BUF][0] +                 \
                                   (wc * 144 + nj * 16 + ln) * 64 + fq);         \
      acc[0][nj] = __builtin_amdgcn_mfma_f32_16x16x32_bf16(af0, bf, acc[0][nj],  \
                                                           0, 0, 0);             \
      acc[1][nj] = __builtin_amdgcn_mfma_f32_16x16x32_bf16(af1, bf, acc[1][nj],  \
                                                           0, 0, 0);             \
    }                                                                            \
  } while (0)

  // prologue
  LOADB(0, 0);
  LOADA(0);
  STAGEA(0);
  LOADA(32);
  __syncthreads();  // drains B(0) DMA + A(1) regs

#pragma unroll 2
  for (int kb = 0; kb < 24; ++kb) {
    const int cur = kb & 1, nxt = cur ^ 1;
    if (kb < 23) {
      LOADB(kb + 1, nxt);   // async DMA into other buffer, hidden under compute
      STAGEA(nxt);          // a0 holds kb+1 data (loaded 1 phase ago)
    }
    if (kb < 22) LOADA((kb + 2) * 32);  // HBM/L3 latency hidden under MFMA phase
    PCOMPUTE(cur);
    __syncthreads();
  }
#undef LOADA
#undef STAGEA
#undef LOADB
#undef PCOMPUTE

  // epilogue. global col n = blockIdx.y*288 + wc*144 + nj*16 + ln
  // role = by*2+wc: 0: Q0..143 (RoPE nj0,1) | 1: Q144..191 + K0..95 (RoPE nj3,4)
  //                 2: K96..191 + V0..47    | 3: V48..191 (V stored [b][dim][t])
  const float R_LG = 0.8304820237218406f;  // log2(10000)/16
#define ROPE2(V0, V1, TPOS)                                         \
  do {                                                              \
    float i0 = (float)(ln >> 1);                                    \
    float f0 = exp2f(-i0 * R_LG);                                   \
    float f1 = exp2f(-(i0 + 8.0f) * R_LG);                          \
    float s0, c0, s1, c1;                                           \
    sincosf((float)(TPOS)*f0, &s0, &c0);                            \
    sincosf((float)(TPOS)*f1, &s1, &c1);                            \
    float p0 = __shfl_xor(V0, 1), p1 = __shfl_xor(V1, 1);           \
    V0 = (ln & 1) ? (V0 * c0 + p0 * s0) : (V0 * c0 - p0 * s0);      \
    V1 = (ln & 1) ? (V1 * c1 + p1 * s1) : (V1 * c1 - p1 * s1);      \
  } while (0)

  const int role = blockIdx.y * 2 + wc;
  if (role == 0) {
#pragma unroll
    for (int mi = 0; mi < 2; ++mi)
#pragma unroll
      for (int r = 0; r < 4; ++r) {
        int row_g = m0 + wr * 32 + mi * 16 + quad * 4 + r;
        int t_pos = row_g & 511;
        float v0 = acc[mi][0][r], v1 = acc[mi][1][r];
        ROPE2(v0, v1, t_pos);
        q_ws[(size_t)row_g * 192 + ln] = f2bf(v0);
        q_ws[(size_t)row_g * 192 + 16 + ln] = f2bf(v1);
#pragma unroll
        for (int nj = 2; nj < 9; ++nj)
          q_ws[(size_t)row_g * 192 + nj * 16 + ln] = f2bf(acc[mi][nj][r]);
      }
  } else if (role == 1) {
#pragma unroll
    for (int mi = 0; mi < 2; ++mi)
#pragma unroll
      for (int r = 0; r < 4; ++r) {
        int row_g = m0 + wr * 32 + mi * 16 + quad * 4 + r;
        int t_pos = row_g & 511;
        float v0 = acc[mi][3][r], v1 = acc[mi][4][r];
        ROPE2(v0, v1, t_pos);
#pragma unroll
        for (int nj = 0; nj < 3; ++nj)
          q_ws[(size_t)row_g * 192 + 144 + nj * 16 + ln] = f2bf(acc[mi][nj][r]);
        k_ws[(size_t)row_g * 192 + ln] = f2bf(v0);
        k_ws[(size_t)row_g * 192 + 16 + ln] = f2bf(v1);
#pragma unroll
        for (int nj = 5; nj < 9; ++nj)
          k_ws[(size_t)row_g * 192 + (nj - 3) * 16 + ln] = f2bf(acc[mi][nj][r]);
      }
  } else if (role == 2) {
#pragma unroll
    for (int mi = 0; mi < 2; ++mi) {
#pragma unroll
      for (int r = 0; r < 4; ++r) {
        int row_g = m0 + wr * 32 + mi * 16 + quad * 4 + r;
#pragma unroll
        for (int nj = 0; nj < 6; ++nj)
          k_ws[(size_t)row_g * 192 + 96 + nj * 16 + ln] = f2bf(acc[mi][nj][r]);
      }
      int rb = m0 + wr * 32 + mi * 16 + quad * 4;
      int bb = rb >> 9, t = rb & 511;
#pragma unroll
      for (int nj = 6; nj < 9; ++nj) {
        ushort4 pv;
        pv.x = f2bf(acc[mi][nj][0]);
        pv.y = f2bf(acc[mi][nj][1]);
        pv.z = f2bf(acc[mi][nj][2]);
        pv.w = f2bf(acc[mi][nj][3]);
        *(ushort4*)&v_ws[((size_t)bb * 192 + (nj - 6) * 16 + ln) * 512 + t] = pv;
      }
    }
  } else {
#pragma unroll
    for (int mi = 0; mi < 2; ++mi) {
      int rb = m0 + wr * 32 + mi * 16 + quad * 4;
      int bb = rb >> 9, t = rb & 511;
#pragma unroll
      for (int nj = 0; nj < 9; ++nj) {
        ushort4 pv;
        pv.x = f2bf(acc[mi][nj][0]);
        pv.y = f2bf(acc[mi][nj][1]);
        pv.z = f2bf(acc[mi][nj][2]);
        pv.w = f2bf(acc[mi][nj][3]);
        *(ushort4*)&v_ws[((size_t)bb * 192 + 48 + nj * 16 + ln) * 512 + t] = pv;
      }
    }
  }
#undef ROPE2
}

// ---------------- kernel 3: causal flash attention (MFMA) ----------------
// grid (8, 64). qt remap: dispatch i and i+256 carry complementary qt
// (CU pair sums to 9 K-tiles). v1 structure (known-good) + s_setprio (T5).
__global__ __launch_bounds__(256) void attn_kernel(
    const unsigned short* __restrict__ q_ws, const unsigned short* __restrict__ k_ws,
    const unsigned short* __restrict__ v_ws, float* __restrict__ out) {
  __shared__ __align__(16) unsigned short K_lds[64 * 200];
  __shared__ __align__(16) unsigned short V_lds[192 * 72];   // V^T: [dim][key]
  __shared__ __align__(16) unsigned short P_lds[4][16 * 72]; // per-wave P
  const int tid = threadIdx.x;
  const int w = tid >> 6, l = tid & 63, quad = l >> 4, ln = l & 15;
  const int b = blockIdx.y;
  const int qt = (blockIdx.y < 32) ? blockIdx.x : 7 - blockIdx.x;
  const int q0 = qt * 64;

  // preload Q A-fragments
  short8 qf[6];
  {
    const unsigned short* qp =
        q_ws + (size_t)(b * 512 + q0 + w * 16 + ln) * 192 + quad * 8;
#pragma unroll
    for (int kk = 0; kk < 6; ++kk) qf[kk] = *(const short8*)(qp + kk * 32);
  }

  float m_i[4], l_i[4];
  floatx4 o[12];
#pragma unroll
  for (int r = 0; r < 4; ++r) { m_i[r] = -1e30f; l_i[r] = 0.f; }
#pragma unroll
  for (int nt = 0; nt < 12; ++nt) o[nt] = floatx4{0.f, 0.f, 0.f, 0.f};
  const float sm_scale = 0.07216878364870323f;  // 192^-0.5

  for (int kt = 0; kt <= qt; ++kt) {
    const int k0 = kt * 64;
    __syncthreads();  // previous iteration's LDS reads done before overwrite
    // stage K tile [64][192]
#pragma unroll
    for (int it = 0; it < 6; ++it) {
      int idx = it * 256 + tid;
      int row = idx / 24, c = idx - row * 24;
      uint4 v = *(const uint4*)(k_ws + (size_t)(b * 512 + k0 + row) * 192 + c * 8);
      *(uint4*)&K_lds[row * 200 + c * 8] = v;
    }
    // stage V^T tile [192][64]
#pragma unroll
    for (int it = 0; it < 6; ++it) {
      int idx = it * 256 + tid;
      int row = idx >> 3, c = idx & 7;
      uint4 v = *(const uint4*)(v_ws + (size_t)(b * 192 + row) * 512 + k0 + c * 8);
      *(uint4*)&V_lds[row * 72 + c * 8] = v;
    }
    __syncthreads();

    // S = Q K^T (scaled)
    float s[4][4];
    __builtin_amdgcn_s_setprio(1);
#pragma unroll
    for (int nt = 0; nt < 4; ++nt) {
      floatx4 sa = floatx4{0.f, 0.f, 0.f, 0.f};
#pragma unroll
      for (int kk = 0; kk < 6; ++kk) {
        short8 kf = *(const short8*)&K_lds[(nt * 16 + ln) * 200 + kk * 32 + quad * 8];
        sa = __builtin_amdgcn_mfma_f32_16x16x32_bf16(qf[kk], kf, sa, 0, 0, 0);
      }
#pragma unroll
      for (int r = 0; r < 4; ++r) s[nt][r] = sa[r] * sm_scale;
    }
    __builtin_amdgcn_s_setprio(0);
    if (kt == qt) {  // diagonal tile mask (k0 == q0)
#pragma unroll
      for (int nt = 0; nt < 4; ++nt)
#pragma unroll
        for (int r = 0; r < 4; ++r)
          if (nt * 16 + ln > w * 16 + quad * 4 + r) s[nt][r] = -1e30f;
    }
    // online softmax (row = quad*4+r)
    float alpha[4];
#pragma unroll
    for (int r = 0; r < 4; ++r) {
      float mx = fmaxf(fmaxf(s[0][r], s[1][r]), fmaxf(s[2][r], s[3][r]));
      mx = fmaxf(mx, __shfl_xor(mx, 1));
      mx = fmaxf(mx, __shfl_xor(mx, 2));
      mx = fmaxf(mx, __shfl_xor(mx, 4));
      mx = fmaxf(mx, __shfl_xor(mx, 8));
      float mnew = fmaxf(m_i[r], mx);
      alpha[r] = __expf(m_i[r] - mnew);
      float sum = 0.f;
#pragma unroll
      for (int nt = 0; nt < 4; ++nt) {
        s[nt][r] = __expf(s[nt][r] - mnew);
        sum += s[nt][r];
      }
      sum += __shfl_xor(sum, 1);
      sum += __shfl_xor(sum, 2);
      sum += __shfl_xor(sum, 4);
      sum += __shfl_xor(sum, 8);
      l_i[r] = l_i[r] * alpha[r] + sum;
      m_i[r] = mnew;
    }
#pragma unroll
    for (int nt = 0; nt < 12; ++nt)
#pragma unroll
      for (int r = 0; r < 4; ++r) o[nt][r] *= alpha[r];

    // P: C/D layout -> A layout via per-wave LDS
#pragma unroll
    for (int nt = 0; nt < 4; ++nt)
#pragma unroll
      for (int r = 0; r < 4; ++r)
        P_lds[w][(quad * 4 + r) * 72 + nt * 16 + ln] = f2bf(s[nt][r]);
    __asm__ volatile("s_waitcnt lgkmcnt(0)" ::: "memory");  // wave-local write->read

    // O += P V
    __builtin_amdgcn_s_setprio(1);
#pragma unroll
    for (int ks = 0; ks < 2; ++ks) {
      short8 pf = *(const short8*)&P_lds[w][ln * 72 + ks * 32 + quad * 8];
#pragma unroll
      for (int nt = 0; nt < 12; ++nt) {
        short8 vf = *(const short8*)&V_lds[(nt * 16 + ln) * 72 + ks * 32 + quad * 8];
        o[nt] = __builtin_amdgcn_mfma_f32_16x16x32_bf16(pf, vf, o[nt], 0, 0, 0);
      }
    }
    __builtin_amdgcn_s_setprio(0);
  }

  // epilogue: O/l -> fp32 out [b][t][dim]
#pragma unroll
  for (int r = 0; r < 4; ++r) {
    float inv = 1.0f / l_i[r];
    size_t rowoff = (size_t)(b * 512 + q0 + w * 16 + quad * 4 + r) * 192;
#pragma unroll
    for (int nt = 0; nt < 12; ++nt)
      out[rowoff + nt * 16 + ln] = o[nt][r] * inv;
  }
}

extern "C" void kernel_launch(void* const* d_in, const int* in_sizes, int n_in,
                              void* d_out, int out_size, void* d_ws, size_t ws_size,
                              hipStream_t stream) {
  const float* x = (const float*)d_in[0];
  const float* Wq = (const float*)d_in[1];
  const float* Wk = (const float*)d_in[2];
  const float* Wv = (const float*)d_in[3];
  float* out = (float*)d_out;

  char* ws = (char*)d_ws;
  const size_t QKV_BYTES = (size_t)64 * 512 * 192 * 2;  // 12,582,912
  unsigned short* q_ws = (unsigned short*)(ws);
  unsigned short* k_ws = (unsigned short*)(ws + QKV_BYTES);
  unsigned short* v_ws = (unsigned short*)(ws + 2 * QKV_BYTES);
  unsigned short* Wt = (unsigned short*)(ws + 3 * QKV_BYTES);  // 884,736 B image

  hipLaunchKernelGGL(prep_w_kernel, dim3(216), dim3(256), 0, stream, Wq, Wk, Wv, Wt);
  hipLaunchKernelGGL(proj_kernel, dim3(512, 2), dim3(256), 0, stream, x, Wt, q_ws, k_ws, v_ws);
  hipLaunchKernelGGL(attn_kernel, dim3(8, 64), dim3(256), 0, stream, q_ws, k_ws, v_ws, out);
}